// Round 7
// baseline (237.790 us; speedup 1.0000x reference)
//
#include <hip/hip_runtime.h>
#include <hip/hip_bf16.h>
#include <stdint.h>
#include <math.h>

#define B_ 2
#define T_ 2048
#define D_ 1024
#define H_ 16
#define HD_ 64
#define M_ 4096   // B_*T_

using bf16 = __hip_bfloat16;
using short8 = __attribute__((ext_vector_type(8))) short;
using f32x4 = __attribute__((ext_vector_type(4))) float;

// async global->LDS, 16B per lane. LDS dest must be wave-uniform base + lane*16.
__device__ __forceinline__ void async16(const void* g, void* l) {
  __builtin_amdgcn_global_load_lds((const __attribute__((address_space(1))) void*)g,
                                   (__attribute__((address_space(3))) void*)l, 16, 0, 0);
}

// ---------------- prep: 4x weight transpose (fp32->bf16) + x cast, one launch ----------------
__global__ __launch_bounds__(256) void prep_kernel(const float* __restrict__ wq, const float* __restrict__ wk,
                                                   const float* __restrict__ wv, const float* __restrict__ wo,
                                                   const float* __restrict__ x,
                                                   bf16* __restrict__ wt, bf16* __restrict__ xb) {
  const int z = blockIdx.z;
  const int tx = threadIdx.x, ty = threadIdx.y;   // (32,8)
  if (z < 4) {
    __shared__ float tile[32][33];
    const float* src = z==0?wq:z==1?wk:z==2?wv:wo;
    bf16* dst = wt + ((size_t)z << 20);
    const int row0 = blockIdx.y*32;
    const int col  = blockIdx.x*32 + tx;
    #pragma unroll
    for (int j=ty; j<32; j+=8) tile[j][tx] = src[(size_t)(row0+j)*D_ + col];
    __syncthreads();
    const int ocol  = row0 + tx;
    const int orow0 = blockIdx.x*32;
    #pragma unroll
    for (int j=ty; j<32; j+=8) dst[(size_t)(orow0+j)*D_ + ocol] = __float2bfloat16(tile[tx][j]);
  } else {
    const int tid = ty*32 + tx;
    const size_t base = ((size_t)(blockIdx.y*32 + blockIdx.x))*4096 + (size_t)tid*16;
    #pragma unroll
    for (int h=0; h<2; ++h) {
      float4 a = *(const float4*)(x + base + h*8);
      float4 b = *(const float4*)(x + base + h*8 + 4);
      bf16 o[8] = { __float2bfloat16(a.x), __float2bfloat16(a.y), __float2bfloat16(a.z), __float2bfloat16(a.w),
                    __float2bfloat16(b.x), __float2bfloat16(b.y), __float2bfloat16(b.z), __float2bfloat16(b.w) };
      *(uint4*)(xb + base + h*8) = *(const uint4*)o;
    }
  }
}

// ---------------- fused QKV GEMM: [4096,1024] @ [1024,3072] + bias ----------------
// out layouts: Q (pre-scaled by 1/sqrt(64)*log2e), K = [b][h][t][hd]; V = [b][h][hd][t]
__global__ __launch_bounds__(256,1) void qkv_gemm(const bf16* __restrict__ X, const bf16* __restrict__ Wt,
                                                  const float* __restrict__ bq, const float* __restrict__ bk,
                                                  const float* __restrict__ bv,
                                                  bf16* __restrict__ Qb, bf16* __restrict__ Kb, bf16* __restrict__ Vb) {
  __shared__ bf16 As[128*32];
  __shared__ bf16 Bs[128*32];
  const int tid = threadIdx.x;
  const int lane = tid & 63, wave = tid >> 6;
  const int quad = lane >> 4, l16 = lane & 15;
  const int wm = (wave >> 1) * 64, wn = (wave & 1) * 64;
  const int m0  = blockIdx.x * 128;
  const int nt0 = blockIdx.y * 128;          // 0..3071
  const int which = nt0 >> 10;               // 0=Q 1=K 2=V
  const int n0 = nt0 & 1023;
  const bf16* W = Wt + ((size_t)which << 20);
  const float* bias = which==0 ? bq : (which==1 ? bk : bv);
  const bool vmode = (which == 2);
  const float oscale = (which==0) ? 0.125f * 1.44269504088896340736f : 1.0f;

  f32x4 acc[4][4];
  #pragma unroll
  for (int i=0;i<4;i++)
    #pragma unroll
    for (int j=0;j<4;j++) acc[i][j] = (f32x4){0.f,0.f,0.f,0.f};

  for (int k0 = 0; k0 < 1024; k0 += 32) {
    __syncthreads();
    #pragma unroll
    for (int it=0; it<2; ++it) {
      int id = tid + it*256;               // 0..511
      int row = id >> 2, seg = id & 3;
      async16(X + (size_t)(m0+row)*1024 + k0 + seg*8, (char*)As + id*16);
      async16(W + (size_t)(n0+row)*1024 + k0 + seg*8, (char*)Bs + id*16);
    }
    __syncthreads();   // drains vmcnt before barrier -> LDS valid
    const bf16* Asrc = vmode ? Bs : As;
    const bf16* Bsrc = vmode ? As : Bs;
    short8 af[4], bfv[4];
    #pragma unroll
    for (int i=0;i<4;i++) af[i]  = *(const short8*)(Asrc + (wm + i*16 + l16)*32 + quad*8);
    #pragma unroll
    for (int j=0;j<4;j++) bfv[j] = *(const short8*)(Bsrc + (wn + j*16 + l16)*32 + quad*8);
    #pragma unroll
    for (int i=0;i<4;i++)
      #pragma unroll
      for (int j=0;j<4;j++)
        acc[i][j] = __builtin_amdgcn_mfma_f32_16x16x32_bf16(af[i], bfv[j], acc[i][j], 0, 0, 0);
  }

  if (!vmode) {
    bf16* out = (which==0) ? Qb : Kb;
    #pragma unroll
    for (int i=0;i<4;i++) {
      #pragma unroll
      for (int j=0;j<4;j++) {
        const int n = n0 + wn + j*16 + l16;
        const float bvv = bias[n];
        const int h = n >> 6, hd = n & 63;
        #pragma unroll
        for (int r=0;r<4;r++) {
          const int m = m0 + wm + i*16 + quad*4 + r;
          const int b = m >> 11, t = m & 2047;
          out[(((size_t)b*H_ + h)*T_ + t)*HD_ + hd] = __float2bfloat16((acc[i][j][r] + bvv) * oscale);
        }
      }
    }
  } else {
    #pragma unroll
    for (int i=0;i<4;i++) {
      #pragma unroll
      for (int r=0;r<4;r++) {
        const int n = n0 + wm + i*16 + quad*4 + r;
        const float bvv = bias[n];
        const int h = n >> 6, hd = n & 63;
        #pragma unroll
        for (int j=0;j<4;j++) {
          const int m = m0 + wn + j*16 + l16;
          const int b = m >> 11, t = m & 2047;
          Vb[(((size_t)b*H_ + h)*HD_ + hd)*T_ + t] = __float2bfloat16(acc[i][j][r] + bvv);
        }
      }
    }
  }
}

// ---------------- flash attention v6: 3 blocks/CU (Q staged into dbuf[1], no Qs) ----------------
// swizzled LDS tile: 64 rows x 64 bf16; chunk (8 elems) stored at (chunk ^ (row&7))
__device__ __forceinline__ void stage64x64(const bf16* __restrict__ g, size_t gstride, bf16* lds,
                                           int wave, int lane) {
  const int lr = lane >> 3;           // row within 8-row group
  const int c  = (lane & 7) ^ lr;     // global chunk this lane fetches
  #pragma unroll
  for (int it = 0; it < 2; ++it) {
    const int group = wave * 2 + it;  // 0..7
    async16(g + (size_t)(group*8 + lr)*gstride + c*8, lds + group*512 + lane*8);
  }
}

__device__ __forceinline__ short8 read_swz(const bf16* lds, int row, int chunk) {
  return *(const short8*)(lds + row*64 + ((chunk ^ (row & 7)) << 3));
}

#define PSTR 36   // P strip stride (bf16), 32 keys + pad

__global__ __launch_bounds__(256,3) void attn_kernel(const bf16* __restrict__ Qg, const bf16* __restrict__ Kg,
                                                     const bf16* __restrict__ Vg, bf16* __restrict__ Og) {
  __shared__ bf16 Kd[2][64*64];       // double-buffered keys x hd; Kd[1] holds Q rows 0-63 pre-loop
  __shared__ bf16 Vd[2][64*64];       // double-buffered hd x keys; Vd[1] holds Q rows 64-127 pre-loop
  __shared__ bf16 Ps[4][4][16*PSTR];  // per-wave, per-strip P [query16][key32]; reused as fp32 O-exchange
  __shared__ float Lred[2][2][4][16]; // [qhalf][khalf][strip][q16]

  const int tid = threadIdx.x;
  const int lane = tid & 63, wave = tid >> 6;
  const int quad = lane >> 4, l16 = lane & 15;
  const int qhalf = wave & 1, khalf = wave >> 1;
  const int bh = blockIdx.y;
  const int q0 = blockIdx.x * 128;

  const bf16* Qp = Qg + (size_t)bh*T_*HD_;
  const bf16* Kp = Kg + (size_t)bh*T_*HD_;
  const bf16* Vp = Vg + (size_t)bh*HD_*T_;

  // Q -> the [1] buffers (dead until iteration 0's prefetch); K0/V0 -> the [0] buffers
  stage64x64(Qp + (size_t)q0*HD_,      HD_, Kd[1], wave, lane);
  stage64x64(Qp + (size_t)(q0+64)*HD_, HD_, Vd[1], wave, lane);
  stage64x64(Kp, HD_, Kd[0], wave, lane);
  stage64x64(Vp, T_,  Vd[0], wave, lane);
  __syncthreads();   // drains all initial staging DMA

  const bf16* Qsrc = qhalf ? Vd[1] : Kd[1];
  short8 qf[4][2];   // [strip][ks]; strip s covers queries qhalf*64 + s*16 + [0,16)
  #pragma unroll
  for (int s=0; s<4; ++s)
    #pragma unroll
    for (int ks=0; ks<2; ++ks)
      qf[s][ks] = read_swz(Qsrc, s*16 + l16, ks*4 + quad);
  __syncthreads();   // all waves have their Q fragments before [1] is overwritten

  f32x4 o_acc[4][4];
  float l_part[4] = {0.f, 0.f, 0.f, 0.f};
  #pragma unroll
  for (int s=0;s<4;s++)
    #pragma unroll
    for (int jv=0;jv<4;jv++) o_acc[s][jv] = (f32x4){0.f,0.f,0.f,0.f};

  const int krow = khalf * 32;
  const int NT = T_/64;

  for (int kt=0; kt<NT; ++kt) {
    const int cur = kt & 1;
    if (kt+1 < NT) {
      stage64x64(Kp + (size_t)(kt+1)*64*HD_, HD_, Kd[1-cur], wave, lane);
      stage64x64(Vp + (size_t)(kt+1)*64,     T_,  Vd[1-cur], wave, lane);
    }
    const bf16* Ks  = Kd[cur];
    const bf16* Vts = Vd[cur];

    // this wave's key-half fragments
    short8 kf[2][2];   // [jb][ks]
    #pragma unroll
    for (int jb=0; jb<2; ++jb)
      #pragma unroll
      for (int ks=0; ks<2; ++ks)
        kf[jb][ks] = read_swz(Ks, krow + jb*16 + l16, ks*4 + quad);
    short8 vf[4];      // [jv] : V[key=khalf*32+quad*8+j][hd=jv*16+l16]
    #pragma unroll
    for (int jv=0; jv<4; ++jv)
      vf[jv] = read_swz(Vts, jv*16 + l16, khalf*4 + quad);

    // phase 1: QK + softmax for all strips (stores to per-strip P buffers)
    #pragma unroll
    for (int s=0; s<4; ++s) {
      f32x4 sc[2];
      sc[0] = (f32x4){0.f,0.f,0.f,0.f};
      sc[1] = (f32x4){0.f,0.f,0.f,0.f};
      #pragma unroll
      for (int ks=0; ks<2; ++ks)
        #pragma unroll
        for (int jb=0; jb<2; ++jb)
          sc[jb] = __builtin_amdgcn_mfma_f32_16x16x32_bf16(kf[jb][ks], qf[s][ks], sc[jb], 0, 0, 0);
      bf16* Pw = &Ps[wave][s][0];
      #pragma unroll
      for (int jb=0; jb<2; ++jb) {
        bf16 pk[4];
        #pragma unroll
        for (int r=0; r<4; ++r) {
          float pv = __builtin_amdgcn_exp2f(sc[jb][r]);
          l_part[s] += pv;
          pk[r] = __float2bfloat16(pv);
        }
        *(uint2*)(&Pw[l16*PSTR + jb*16 + quad*4]) = *(const uint2*)pk;
      }
    }

    // phase 2: PV for all strips (one lgkm drain, then MFMA burst)
    #pragma unroll
    for (int s=0; s<4; ++s) {
      short8 pf = *(const short8*)(&Ps[wave][s][l16*PSTR + quad*8]);
      #pragma unroll
      for (int jv=0; jv<4; ++jv)
        o_acc[s][jv] = __builtin_amdgcn_mfma_f32_16x16x32_bf16(pf, vf[jv], o_acc[s][jv], 0, 0, 0);
    }

    __syncthreads();   // all waves done with cur tile; drains prefetch DMA
  }

  // l: reduce over quads (keys within this wave's half), publish, combine key-halves
  #pragma unroll
  for (int s=0; s<4; ++s) {
    float l = l_part[s];
    l += __shfl_xor(l, 16);
    l += __shfl_xor(l, 32);
    l_part[s] = l;
  }
  if (lane < 16) {
    #pragma unroll
    for (int s=0; s<4; ++s) Lred[qhalf][khalf][s][lane] = l_part[s];
  }
  __syncthreads();
  float linv[4][4];
  #pragma unroll
  for (int s=0; s<4; ++s)
    #pragma unroll
    for (int r=0; r<4; ++r)
      linv[s][r] = 1.0f / (Lred[qhalf][0][s][quad*4+r] + Lred[qhalf][1][s][quad*4+r]);

  // O reduction across key-halves through dead Ps region (16KB), 2 rounds x 8KB
  f32x4* xb = (f32x4*)&Ps[0][0][0];
  #pragma unroll
  for (int round=0; round<2; ++round) {
    const int sB = round*2;
    if (khalf == 1) {
      #pragma unroll
      for (int s2=0; s2<2; ++s2)
        #pragma unroll
        for (int jv=0; jv<4; ++jv)
          xb[qhalf*512 + s2*256 + jv*64 + lane] = o_acc[sB+s2][jv];
    }
    __syncthreads();
    if (khalf == 0) {
      #pragma unroll
      for (int s2=0; s2<2; ++s2)
        #pragma unroll
        for (int jv=0; jv<4; ++jv)
          o_acc[sB+s2][jv] += xb[qhalf*512 + s2*256 + jv*64 + lane];
    }
    __syncthreads();
  }

  // epilogue: khalf==0 waves hold full sums; write O as [b][t][h*64+hd]
  if (khalf == 0) {
    const int b = bh >> 4, h = bh & 15;
    #pragma unroll
    for (int s=0; s<4; ++s)
      #pragma unroll
      for (int jv=0; jv<4; ++jv)
        #pragma unroll
        for (int r=0; r<4; ++r) {
          const int row = q0 + qhalf*64 + s*16 + quad*4 + r;
          const float ov = o_acc[s][jv][r] * linv[s][r];
          Og[((size_t)b*T_ + row)*D_ + h*HD_ + jv*16 + l16] = __float2bfloat16(ov);
        }
  }
}

// ---------------- output projection + bias + residual(fp32) -> fp32 tmp ----------------
__global__ __launch_bounds__(256,1) void proj_gemm(const bf16* __restrict__ A, const bf16* __restrict__ Wt,
                                                   const float* __restrict__ bo, const float* __restrict__ Xres,
                                                   float* __restrict__ tmp) {
  __shared__ bf16 As[128*32];
  __shared__ bf16 Bs[128*32];
  const int tid = threadIdx.x;
  const int lane = tid & 63, wave = tid >> 6;
  const int quad = lane >> 4, l16 = lane & 15;
  const int wm = (wave >> 1) * 64, wn = (wave & 1) * 64;
  const int m0 = blockIdx.x * 128;
  const int n0 = blockIdx.y * 128;

  f32x4 acc[4][4];
  #pragma unroll
  for (int i=0;i<4;i++)
    #pragma unroll
    for (int j=0;j<4;j++) acc[i][j] = (f32x4){0.f,0.f,0.f,0.f};

  for (int k0 = 0; k0 < 1024; k0 += 32) {
    __syncthreads();
    #pragma unroll
    for (int it=0; it<2; ++it) {
      int id = tid + it*256;
      int row = id >> 2, seg = id & 3;
      async16(A  + (size_t)(m0+row)*1024 + k0 + seg*8, (char*)As + id*16);
      async16(Wt + (size_t)(n0+row)*1024 + k0 + seg*8, (char*)Bs + id*16);
    }
    __syncthreads();
    short8 af[4], bfv[4];
    #pragma unroll
    for (int i=0;i<4;i++) af[i]  = *(const short8*)(As + (wm + i*16 + l16)*32 + quad*8);
    #pragma unroll
    for (int j=0;j<4;j++) bfv[j] = *(const short8*)(Bs + (wn + j*16 + l16)*32 + quad*8);
    #pragma unroll
    for (int i=0;i<4;i++)
      #pragma unroll
      for (int j=0;j<4;j++)
        acc[i][j] = __builtin_amdgcn_mfma_f32_16x16x32_bf16(af[i], bfv[j], acc[i][j], 0, 0, 0);
  }

  #pragma unroll
  for (int i=0;i<4;i++) {
    #pragma unroll
    for (int j=0;j<4;j++) {
      const int n = n0 + wn + j*16 + l16;
      const float bvv = bo[n];
      #pragma unroll
      for (int r=0;r<4;r++) {
        const int m = m0 + wm + i*16 + quad*4 + r;
        tmp[(size_t)m*1024 + n] = acc[i][j][r] + bvv + Xres[(size_t)m*1024 + n];
      }
    }
  }
}

// ---------------- row LayerNorm: tmp fp32 [4096][1024] -> fp32 out ----------------
__global__ __launch_bounds__(256) void ln_kernel(const float* __restrict__ tmp, const float* __restrict__ g,
                                                 const float* __restrict__ b, float* __restrict__ out) {
  const int row = blockIdx.x;
  const int tid = threadIdx.x;
  const float* p = tmp + (size_t)row*D_;
  float4 v = *(const float4*)(p + tid*4);
  float s  = v.x + v.y + v.z + v.w;
  float sq = v.x*v.x + v.y*v.y + v.z*v.z + v.w*v.w;
  #pragma unroll
  for (int off=32; off>0; off>>=1) { s += __shfl_down(s, off); sq += __shfl_down(sq, off); }
  __shared__ float red[8];
  __shared__ float stats[2];
  const int wave = tid >> 6, lane = tid & 63;
  if (lane == 0) { red[wave] = s; red[4+wave] = sq; }
  __syncthreads();
  if (tid == 0) {
    float S = red[0]+red[1]+red[2]+red[3];
    float Q = red[4]+red[5]+red[6]+red[7];
    float mu = S * (1.0f/D_);
    float var = Q * (1.0f/D_) - mu*mu;
    stats[0] = mu;
    stats[1] = rsqrtf(var + 1e-5f);
  }
  __syncthreads();
  const float mu = stats[0], rstd = stats[1];
  const float vals[4] = {v.x, v.y, v.z, v.w};
  float4 o;
  float* op = (float*)&o;
  #pragma unroll
  for (int c=0;c<4;c++) op[c] = (vals[c]-mu)*rstd*g[tid*4+c] + b[tid*4+c];
  *(float4*)(out + (size_t)row*D_ + tid*4) = o;
}

extern "C" void kernel_launch(void* const* d_in, const int* in_sizes, int n_in,
                              void* d_out, int out_size, void* d_ws, size_t ws_size,
                              hipStream_t stream) {
  (void)in_sizes; (void)n_in; (void)out_size; (void)ws_size;
  const float* x  = (const float*)d_in[0];
  const float* Wq = (const float*)d_in[1];
  const float* bq = (const float*)d_in[2];
  const float* Wk = (const float*)d_in[3];
  const float* bk = (const float*)d_in[4];
  const float* Wv = (const float*)d_in[5];
  const float* bv = (const float*)d_in[6];
  const float* Wo = (const float*)d_in[7];
  const float* bo = (const float*)d_in[8];
  const float* lg = (const float*)d_in[9];
  const float* lb = (const float*)d_in[10];
  float* out = (float*)d_out;

  char* ws = (char*)d_ws;
  bf16* wt  = (bf16*)ws;  ws += (size_t)4*1024*1024*sizeof(bf16);   // W transposed, bf16 (8 MB)
  bf16* Xb  = (bf16*)ws;  ws += (size_t)M_*D_*sizeof(bf16);         // x bf16 (8 MB)
  bf16* Vb  = (bf16*)ws;  ws += (size_t)M_*D_*sizeof(bf16);         // V^T (8 MB)
  bf16* Ob  = (bf16*)ws;  ws += (size_t)M_*D_*sizeof(bf16);         // attn out (8 MB)
  bf16* Qb  = (bf16*)ws;  ws += (size_t)M_*D_*sizeof(bf16);         // Q (8 MB)
  bf16* Kb  = (bf16*)ws;  ws += (size_t)M_*D_*sizeof(bf16);         // K (8 MB)
  float* tmp = (float*)Qb;   // fp32 [4096][1024] overlays Q+K (dead after attention)

  prep_kernel<<<dim3(32,32,5), dim3(32,8), 0, stream>>>(Wq, Wk, Wv, Wo, x, wt, Xb);
  qkv_gemm<<<dim3(32,24), 256, 0, stream>>>(Xb, wt, bq, bk, bv, Qb, Kb, Vb);
  attn_kernel<<<dim3(T_/128, B_*H_), 256, 0, stream>>>(Qb, Kb, Vb, Ob);
  proj_gemm<<<dim3(32,8), 256, 0, stream>>>(Ob, wt + (size_t)3*1024*1024, bo, x, tmp);
  ln_kernel<<<M_, 256, 0, stream>>>(tmp, lg, lb, out);
}

// Round 8
// 212.983 us; speedup vs baseline: 1.1165x; 1.1165x over previous
//
#include <hip/hip_runtime.h>
#include <hip/hip_bf16.h>
#include <stdint.h>
#include <math.h>

#define B_ 2
#define T_ 2048
#define D_ 1024
#define H_ 16
#define HD_ 64
#define M_ 4096   // B_*T_

using bf16 = __hip_bfloat16;
using short8 = __attribute__((ext_vector_type(8))) short;
using f32x4 = __attribute__((ext_vector_type(4))) float;

// async global->LDS, 16B per lane. LDS dest must be wave-uniform base + lane*16.
__device__ __forceinline__ void async16(const void* g, void* l) {
  __builtin_amdgcn_global_load_lds((const __attribute__((address_space(1))) void*)g,
                                   (__attribute__((address_space(3))) void*)l, 16, 0, 0);
}

// ---------------- prep: 4x weight transpose (fp32->bf16) + x cast, one launch ----------------
__global__ __launch_bounds__(256) void prep_kernel(const float* __restrict__ wq, const float* __restrict__ wk,
                                                   const float* __restrict__ wv, const float* __restrict__ wo,
                                                   const float* __restrict__ x,
                                                   bf16* __restrict__ wt, bf16* __restrict__ xb) {
  const int z = blockIdx.z;
  const int tx = threadIdx.x, ty = threadIdx.y;   // (32,8)
  if (z < 4) {
    __shared__ float tile[32][33];
    const float* src = z==0?wq:z==1?wk:z==2?wv:wo;
    bf16* dst = wt + ((size_t)z << 20);
    const int row0 = blockIdx.y*32;
    const int col  = blockIdx.x*32 + tx;
    #pragma unroll
    for (int j=ty; j<32; j+=8) tile[j][tx] = src[(size_t)(row0+j)*D_ + col];
    __syncthreads();
    const int ocol  = row0 + tx;
    const int orow0 = blockIdx.x*32;
    #pragma unroll
    for (int j=ty; j<32; j+=8) dst[(size_t)(orow0+j)*D_ + ocol] = __float2bfloat16(tile[tx][j]);
  } else {
    const int tid = ty*32 + tx;
    const size_t base = ((size_t)(blockIdx.y*32 + blockIdx.x))*4096 + (size_t)tid*16;
    #pragma unroll
    for (int h=0; h<2; ++h) {
      float4 a = *(const float4*)(x + base + h*8);
      float4 b = *(const float4*)(x + base + h*8 + 4);
      bf16 o[8] = { __float2bfloat16(a.x), __float2bfloat16(a.y), __float2bfloat16(a.z), __float2bfloat16(a.w),
                    __float2bfloat16(b.x), __float2bfloat16(b.y), __float2bfloat16(b.z), __float2bfloat16(b.w) };
      *(uint4*)(xb + base + h*8) = *(const uint4*)o;
    }
  }
}

// ---------------- fused QKV GEMM: [4096,1024] @ [1024,3072] + bias ----------------
// out layouts: Q (pre-scaled by 1/sqrt(64)*log2e), K = [b][h][t][hd]; V = [b][h][hd][t]
__global__ __launch_bounds__(256,1) void qkv_gemm(const bf16* __restrict__ X, const bf16* __restrict__ Wt,
                                                  const float* __restrict__ bq, const float* __restrict__ bk,
                                                  const float* __restrict__ bv,
                                                  bf16* __restrict__ Qb, bf16* __restrict__ Kb, bf16* __restrict__ Vb) {
  __shared__ bf16 As[128*32];
  __shared__ bf16 Bs[128*32];
  const int tid = threadIdx.x;
  const int lane = tid & 63, wave = tid >> 6;
  const int quad = lane >> 4, l16 = lane & 15;
  const int wm = (wave >> 1) * 64, wn = (wave & 1) * 64;
  const int m0  = blockIdx.x * 128;
  const int nt0 = blockIdx.y * 128;          // 0..3071
  const int which = nt0 >> 10;               // 0=Q 1=K 2=V
  const int n0 = nt0 & 1023;
  const bf16* W = Wt + ((size_t)which << 20);
  const float* bias = which==0 ? bq : (which==1 ? bk : bv);
  const bool vmode = (which == 2);
  const float oscale = (which==0) ? 0.125f * 1.44269504088896340736f : 1.0f;

  f32x4 acc[4][4];
  #pragma unroll
  for (int i=0;i<4;i++)
    #pragma unroll
    for (int j=0;j<4;j++) acc[i][j] = (f32x4){0.f,0.f,0.f,0.f};

  for (int k0 = 0; k0 < 1024; k0 += 32) {
    __syncthreads();
    #pragma unroll
    for (int it=0; it<2; ++it) {
      int id = tid + it*256;               // 0..511
      int row = id >> 2, seg = id & 3;
      async16(X + (size_t)(m0+row)*1024 + k0 + seg*8, (char*)As + id*16);
      async16(W + (size_t)(n0+row)*1024 + k0 + seg*8, (char*)Bs + id*16);
    }
    __syncthreads();   // drains vmcnt before barrier -> LDS valid
    const bf16* Asrc = vmode ? Bs : As;
    const bf16* Bsrc = vmode ? As : Bs;
    short8 af[4], bfv[4];
    #pragma unroll
    for (int i=0;i<4;i++) af[i]  = *(const short8*)(Asrc + (wm + i*16 + l16)*32 + quad*8);
    #pragma unroll
    for (int j=0;j<4;j++) bfv[j] = *(const short8*)(Bsrc + (wn + j*16 + l16)*32 + quad*8);
    #pragma unroll
    for (int i=0;i<4;i++)
      #pragma unroll
      for (int j=0;j<4;j++)
        acc[i][j] = __builtin_amdgcn_mfma_f32_16x16x32_bf16(af[i], bfv[j], acc[i][j], 0, 0, 0);
  }

  if (!vmode) {
    bf16* out = (which==0) ? Qb : Kb;
    #pragma unroll
    for (int i=0;i<4;i++) {
      #pragma unroll
      for (int j=0;j<4;j++) {
        const int n = n0 + wn + j*16 + l16;
        const float bvv = bias[n];
        const int h = n >> 6, hd = n & 63;
        #pragma unroll
        for (int r=0;r<4;r++) {
          const int m = m0 + wm + i*16 + quad*4 + r;
          const int b = m >> 11, t = m & 2047;
          out[(((size_t)b*H_ + h)*T_ + t)*HD_ + hd] = __float2bfloat16((acc[i][j][r] + bvv) * oscale);
        }
      }
    }
  } else {
    #pragma unroll
    for (int i=0;i<4;i++) {
      #pragma unroll
      for (int r=0;r<4;r++) {
        const int n = n0 + wm + i*16 + quad*4 + r;
        const float bvv = bias[n];
        const int h = n >> 6, hd = n & 63;
        #pragma unroll
        for (int j=0;j<4;j++) {
          const int m = m0 + wn + j*16 + l16;
          const int b = m >> 11, t = m & 2047;
          Vb[(((size_t)b*H_ + h)*HD_ + hd)*T_ + t] = __float2bfloat16(acc[i][j][r] + bvv);
        }
      }
    }
  }
}

// ---------------- flash attention v5 (round-6 revert): 64q x 32k per wave, key-split waves ----------------
// swizzled LDS tile: 64 rows x 64 bf16; chunk (8 elems) stored at (chunk ^ (row&7))
__device__ __forceinline__ void stage64x64(const bf16* __restrict__ g, size_t gstride, bf16* lds,
                                           int wave, int lane) {
  const int lr = lane >> 3;           // row within 8-row group
  const int c  = (lane & 7) ^ lr;     // global chunk this lane fetches
  #pragma unroll
  for (int it = 0; it < 2; ++it) {
    const int group = wave * 2 + it;  // 0..7
    async16(g + (size_t)(group*8 + lr)*gstride + c*8, lds + group*512 + lane*8);
  }
}

__device__ __forceinline__ short8 read_swz(const bf16* lds, int row, int chunk) {
  return *(const short8*)(lds + row*64 + ((chunk ^ (row & 7)) << 3));
}

#define PSTR 36   // P strip stride (bf16), 32 keys + pad

__global__ __launch_bounds__(256,2) void attn_kernel(const bf16* __restrict__ Qg, const bf16* __restrict__ Kg,
                                                     const bf16* __restrict__ Vg, bf16* __restrict__ Og) {
  __shared__ bf16 Qs[128*64];         // 128 q-rows swizzled; reused as fp32 O-exchange (16KB)
  __shared__ bf16 Kd[2][64*64];       // double-buffered keys x hd
  __shared__ bf16 Vd[2][64*64];       // double-buffered hd x keys
  __shared__ bf16 Ps[4][4][16*PSTR];  // per-wave, per-strip P [query16][key32]
  __shared__ float Lred[2][2][4][16]; // [qhalf][khalf][strip][q16]

  const int tid = threadIdx.x;
  const int lane = tid & 63, wave = tid >> 6;
  const int quad = lane >> 4, l16 = lane & 15;
  const int qhalf = wave & 1, khalf = wave >> 1;
  const int bh = blockIdx.y;
  const int q0 = blockIdx.x * 128;

  const bf16* Qp = Qg + (size_t)bh*T_*HD_;
  const bf16* Kp = Kg + (size_t)bh*T_*HD_;
  const bf16* Vp = Vg + (size_t)bh*HD_*T_;

  stage64x64(Qp + (size_t)q0*HD_,      HD_, Qs,       wave, lane);
  stage64x64(Qp + (size_t)(q0+64)*HD_, HD_, Qs+64*64, wave, lane);
  stage64x64(Kp, HD_, Kd[0], wave, lane);
  stage64x64(Vp, T_,  Vd[0], wave, lane);
  __syncthreads();

  short8 qf[4][2];   // [strip][ks]; strip s covers queries qhalf*64 + s*16 + [0,16)
  #pragma unroll
  for (int s=0; s<4; ++s)
    #pragma unroll
    for (int ks=0; ks<2; ++ks)
      qf[s][ks] = read_swz(Qs, qhalf*64 + s*16 + l16, ks*4 + quad);

  f32x4 o_acc[4][4];
  float l_part[4] = {0.f, 0.f, 0.f, 0.f};
  #pragma unroll
  for (int s=0;s<4;s++)
    #pragma unroll
    for (int jv=0;jv<4;jv++) o_acc[s][jv] = (f32x4){0.f,0.f,0.f,0.f};

  const int krow = khalf * 32;
  const int NT = T_/64;

  for (int kt=0; kt<NT; ++kt) {
    const int cur = kt & 1;
    if (kt+1 < NT) {
      stage64x64(Kp + (size_t)(kt+1)*64*HD_, HD_, Kd[1-cur], wave, lane);
      stage64x64(Vp + (size_t)(kt+1)*64,     T_,  Vd[1-cur], wave, lane);
    }
    const bf16* Ks  = Kd[cur];
    const bf16* Vts = Vd[cur];

    // this wave's key-half fragments
    short8 kf[2][2];   // [jb][ks]
    #pragma unroll
    for (int jb=0; jb<2; ++jb)
      #pragma unroll
      for (int ks=0; ks<2; ++ks)
        kf[jb][ks] = read_swz(Ks, krow + jb*16 + l16, ks*4 + quad);
    short8 vf[4];      // [jv] : V[key=khalf*32+quad*8+j][hd=jv*16+l16]
    #pragma unroll
    for (int jv=0; jv<4; ++jv)
      vf[jv] = read_swz(Vts, jv*16 + l16, khalf*4 + quad);

    // phase 1: QK + softmax for all strips (stores to per-strip P buffers)
    #pragma unroll
    for (int s=0; s<4; ++s) {
      f32x4 sc[2];
      sc[0] = (f32x4){0.f,0.f,0.f,0.f};
      sc[1] = (f32x4){0.f,0.f,0.f,0.f};
      #pragma unroll
      for (int ks=0; ks<2; ++ks)
        #pragma unroll
        for (int jb=0; jb<2; ++jb)
          sc[jb] = __builtin_amdgcn_mfma_f32_16x16x32_bf16(kf[jb][ks], qf[s][ks], sc[jb], 0, 0, 0);
      bf16* Pw = &Ps[wave][s][0];
      #pragma unroll
      for (int jb=0; jb<2; ++jb) {
        bf16 pk[4];
        #pragma unroll
        for (int r=0; r<4; ++r) {
          float pv = __builtin_amdgcn_exp2f(sc[jb][r]);
          l_part[s] += pv;
          pk[r] = __float2bfloat16(pv);
        }
        *(uint2*)(&Pw[l16*PSTR + jb*16 + quad*4]) = *(const uint2*)pk;
      }
    }

    // phase 2: PV for all strips (one lgkm drain, then MFMA burst)
    #pragma unroll
    for (int s=0; s<4; ++s) {
      short8 pf = *(const short8*)(&Ps[wave][s][l16*PSTR + quad*8]);
      #pragma unroll
      for (int jv=0; jv<4; ++jv)
        o_acc[s][jv] = __builtin_amdgcn_mfma_f32_16x16x32_bf16(pf, vf[jv], o_acc[s][jv], 0, 0, 0);
    }

    __syncthreads();   // all waves done with cur tile; drains prefetch DMA
  }

  // l: reduce over quads (keys within this wave's half), publish, combine key-halves
  #pragma unroll
  for (int s=0; s<4; ++s) {
    float l = l_part[s];
    l += __shfl_xor(l, 16);
    l += __shfl_xor(l, 32);
    l_part[s] = l;
  }
  if (lane < 16) {
    #pragma unroll
    for (int s=0; s<4; ++s) Lred[qhalf][khalf][s][lane] = l_part[s];
  }
  __syncthreads();
  float linv[4][4];
  #pragma unroll
  for (int s=0; s<4; ++s)
    #pragma unroll
    for (int r=0; r<4; ++r)
      linv[s][r] = 1.0f / (Lred[qhalf][0][s][quad*4+r] + Lred[qhalf][1][s][quad*4+r]);

  // O reduction across key-halves through Qs (dead), 2 rounds x 16KB
  f32x4* xb = (f32x4*)Qs;
  #pragma unroll
  for (int round=0; round<2; ++round) {
    const int sB = round*2;
    if (khalf == 1) {
      #pragma unroll
      for (int s2=0; s2<2; ++s2)
        #pragma unroll
        for (int jv=0; jv<4; ++jv)
          xb[qhalf*512 + s2*256 + jv*64 + lane] = o_acc[sB+s2][jv];
    }
    __syncthreads();
    if (khalf == 0) {
      #pragma unroll
      for (int s2=0; s2<2; ++s2)
        #pragma unroll
        for (int jv=0; jv<4; ++jv)
          o_acc[sB+s2][jv] += xb[qhalf*512 + s2*256 + jv*64 + lane];
    }
    __syncthreads();
  }

  // epilogue: khalf==0 waves hold full sums; write O as [b][t][h*64+hd]
  if (khalf == 0) {
    const int b = bh >> 4, h = bh & 15;
    #pragma unroll
    for (int s=0; s<4; ++s)
      #pragma unroll
      for (int jv=0; jv<4; ++jv)
        #pragma unroll
        for (int r=0; r<4; ++r) {
          const int row = q0 + qhalf*64 + s*16 + quad*4 + r;
          const float ov = o_acc[s][jv][r] * linv[s][r];
          Og[((size_t)b*T_ + row)*D_ + h*HD_ + jv*16 + l16] = __float2bfloat16(ov);
        }
  }
}

// ---------------- output projection + bias + residual(fp32) -> fp32 tmp ----------------
// 128x64 tile -> grid 32x16 = 512 blocks = 2/CU (was 1/CU: exposed barrier drains)
__global__ __launch_bounds__(256,2) void proj_gemm(const bf16* __restrict__ A, const bf16* __restrict__ Wt,
                                                   const float* __restrict__ bo, const float* __restrict__ Xres,
                                                   float* __restrict__ tmp) {
  __shared__ bf16 As[128*32];
  __shared__ bf16 Bs[64*32];
  const int tid = threadIdx.x;
  const int lane = tid & 63, wave = tid >> 6;
  const int quad = lane >> 4, l16 = lane & 15;
  const int wm = wave * 32;
  const int m0 = blockIdx.x * 128;
  const int n0 = blockIdx.y * 64;

  f32x4 acc[2][4];
  #pragma unroll
  for (int i=0;i<2;i++)
    #pragma unroll
    for (int j=0;j<4;j++) acc[i][j] = (f32x4){0.f,0.f,0.f,0.f};

  for (int k0 = 0; k0 < 1024; k0 += 32) {
    __syncthreads();
    #pragma unroll
    for (int it=0; it<2; ++it) {
      int id = tid + it*256;
      int row = id >> 2, seg = id & 3;
      async16(A + (size_t)(m0+row)*1024 + k0 + seg*8, (char*)As + id*16);
    }
    {
      int row = tid >> 2, seg = tid & 3;
      async16(Wt + (size_t)(n0+row)*1024 + k0 + seg*8, (char*)Bs + tid*16);
    }
    __syncthreads();
    short8 af[2], bfv[4];
    #pragma unroll
    for (int i=0;i<2;i++) af[i]  = *(const short8*)(As + (wm + i*16 + l16)*32 + quad*8);
    #pragma unroll
    for (int j=0;j<4;j++) bfv[j] = *(const short8*)(Bs + (j*16 + l16)*32 + quad*8);
    #pragma unroll
    for (int i=0;i<2;i++)
      #pragma unroll
      for (int j=0;j<4;j++)
        acc[i][j] = __builtin_amdgcn_mfma_f32_16x16x32_bf16(af[i], bfv[j], acc[i][j], 0, 0, 0);
  }

  #pragma unroll
  for (int i=0;i<2;i++) {
    #pragma unroll
    for (int j=0;j<4;j++) {
      const int n = n0 + j*16 + l16;
      const float bvv = bo[n];
      #pragma unroll
      for (int r=0;r<4;r++) {
        const int m = m0 + wm + i*16 + quad*4 + r;
        tmp[(size_t)m*1024 + n] = acc[i][j][r] + bvv + Xres[(size_t)m*1024 + n];
      }
    }
  }
}

// ---------------- row LayerNorm: tmp fp32 [4096][1024] -> fp32 out ----------------
__global__ __launch_bounds__(256) void ln_kernel(const float* __restrict__ tmp, const float* __restrict__ g,
                                                 const float* __restrict__ b, float* __restrict__ out) {
  const int row = blockIdx.x;
  const int tid = threadIdx.x;
  const float* p = tmp + (size_t)row*D_;
  float4 v = *(const float4*)(p + tid*4);
  float s  = v.x + v.y + v.z + v.w;
  float sq = v.x*v.x + v.y*v.y + v.z*v.z + v.w*v.w;
  #pragma unroll
  for (int off=32; off>0; off>>=1) { s += __shfl_down(s, off); sq += __shfl_down(sq, off); }
  __shared__ float red[8];
  __shared__ float stats[2];
  const int wave = tid >> 6, lane = tid & 63;
  if (lane == 0) { red[wave] = s; red[4+wave] = sq; }
  __syncthreads();
  if (tid == 0) {
    float S = red[0]+red[1]+red[2]+red[3];
    float Q = red[4]+red[5]+red[6]+red[7];
    float mu = S * (1.0f/D_);
    float var = Q * (1.0f/D_) - mu*mu;
    stats[0] = mu;
    stats[1] = rsqrtf(var + 1e-5f);
  }
  __syncthreads();
  const float mu = stats[0], rstd = stats[1];
  const float vals[4] = {v.x, v.y, v.z, v.w};
  float4 o;
  float* op = (float*)&o;
  #pragma unroll
  for (int c=0;c<4;c++) op[c] = (vals[c]-mu)*rstd*g[tid*4+c] + b[tid*4+c];
  *(float4*)(out + (size_t)row*D_ + tid*4) = o;
}

extern "C" void kernel_launch(void* const* d_in, const int* in_sizes, int n_in,
                              void* d_out, int out_size, void* d_ws, size_t ws_size,
                              hipStream_t stream) {
  (void)in_sizes; (void)n_in; (void)out_size; (void)ws_size;
  const float* x  = (const float*)d_in[0];
  const float* Wq = (const float*)d_in[1];
  const float* bq = (const float*)d_in[2];
  const float* Wk = (const float*)d_in[3];
  const float* bk = (const float*)d_in[4];
  const float* Wv = (const float*)d_in[5];
  const float* bv = (const float*)d_in[6];
  const float* Wo = (const float*)d_in[7];
  const float* bo = (const float*)d_in[8];
  const float* lg = (const float*)d_in[9];
  const float* lb = (const float*)d_in[10];
  float* out = (float*)d_out;

  char* ws = (char*)d_ws;
  bf16* wt  = (bf16*)ws;  ws += (size_t)4*1024*1024*sizeof(bf16);   // W transposed, bf16 (8 MB)
  bf16* Xb  = (bf16*)ws;  ws += (size_t)M_*D_*sizeof(bf16);         // x bf16 (8 MB)
  bf16* Vb  = (bf16*)ws;  ws += (size_t)M_*D_*sizeof(bf16);         // V^T (8 MB)
  bf16* Ob  = (bf16*)ws;  ws += (size_t)M_*D_*sizeof(bf16);         // attn out (8 MB)
  bf16* Qb  = (bf16*)ws;  ws += (size_t)M_*D_*sizeof(bf16);         // Q (8 MB)
  bf16* Kb  = (bf16*)ws;  ws += (size_t)M_*D_*sizeof(bf16);         // K (8 MB)
  float* tmp = (float*)Qb;   // fp32 [4096][1024] overlays Q+K (dead after attention)

  prep_kernel<<<dim3(32,32,5), dim3(32,8), 0, stream>>>(Wq, Wk, Wv, Wo, x, wt, Xb);
  qkv_gemm<<<dim3(32,24), 256, 0, stream>>>(Xb, wt, bq, bk, bv, Qb, Kb, Vb);
  attn_kernel<<<dim3(T_/128, B_*H_), 256, 0, stream>>>(Qb, Kb, Vb, Ob);
  proj_gemm<<<dim3(32,16), 256, 0, stream>>>(Ob, wt + (size_t)3*1024*1024, bo, x, tmp);
  ln_kernel<<<M_, 256, 0, stream>>>(tmp, lg, lb, out);
}

// Round 9
// 208.030 us; speedup vs baseline: 1.1431x; 1.0238x over previous
//
#include <hip/hip_runtime.h>
#include <hip/hip_bf16.h>
#include <stdint.h>
#include <math.h>

#define B_ 2
#define T_ 2048
#define D_ 1024
#define H_ 16
#define HD_ 64
#define M_ 4096   // B_*T_

using bf16 = __hip_bfloat16;
using short8 = __attribute__((ext_vector_type(8))) short;
using f32x4 = __attribute__((ext_vector_type(4))) float;

// async global->LDS, 16B per lane. LDS dest must be wave-uniform base + lane*16.
__device__ __forceinline__ void async16(const void* g, void* l) {
  __builtin_amdgcn_global_load_lds((const __attribute__((address_space(1))) void*)g,
                                   (__attribute__((address_space(3))) void*)l, 16, 0, 0);
}

// ---------------- prep: 4x weight transpose (fp32->bf16) + x cast, one launch ----------------
__global__ __launch_bounds__(256) void prep_kernel(const float* __restrict__ wq, const float* __restrict__ wk,
                                                   const float* __restrict__ wv, const float* __restrict__ wo,
                                                   const float* __restrict__ x,
                                                   bf16* __restrict__ wt, bf16* __restrict__ xb) {
  const int z = blockIdx.z;
  const int tx = threadIdx.x, ty = threadIdx.y;   // (32,8)
  if (z < 4) {
    __shared__ float tile[32][33];
    const float* src = z==0?wq:z==1?wk:z==2?wv:wo;
    bf16* dst = wt + ((size_t)z << 20);
    const int row0 = blockIdx.y*32;
    const int col  = blockIdx.x*32 + tx;
    #pragma unroll
    for (int j=ty; j<32; j+=8) tile[j][tx] = src[(size_t)(row0+j)*D_ + col];
    __syncthreads();
    const int ocol  = row0 + tx;
    const int orow0 = blockIdx.x*32;
    #pragma unroll
    for (int j=ty; j<32; j+=8) dst[(size_t)(orow0+j)*D_ + ocol] = __float2bfloat16(tile[tx][j]);
  } else {
    const int tid = ty*32 + tx;
    const size_t base = ((size_t)(blockIdx.y*32 + blockIdx.x))*4096 + (size_t)tid*16;
    #pragma unroll
    for (int h=0; h<2; ++h) {
      float4 a = *(const float4*)(x + base + h*8);
      float4 b = *(const float4*)(x + base + h*8 + 4);
      bf16 o[8] = { __float2bfloat16(a.x), __float2bfloat16(a.y), __float2bfloat16(a.z), __float2bfloat16(a.w),
                    __float2bfloat16(b.x), __float2bfloat16(b.y), __float2bfloat16(b.z), __float2bfloat16(b.w) };
      *(uint4*)(xb + base + h*8) = *(const uint4*)o;
    }
  }
}

// ---------------- fused QKV GEMM: [4096,1024] @ [1024,3072] + bias ----------------
// BK=64 + XOR chunk swizzle (conflict-free b128 fragment reads, half the barriers)
// out layouts: Q (pre-scaled by 1/sqrt(64)*log2e), K = [b][h][t][hd]; V = [b][h][hd][t]
__global__ __launch_bounds__(256,1) void qkv_gemm(const bf16* __restrict__ X, const bf16* __restrict__ Wt,
                                                  const float* __restrict__ bq, const float* __restrict__ bk,
                                                  const float* __restrict__ bv,
                                                  bf16* __restrict__ Qb, bf16* __restrict__ Kb, bf16* __restrict__ Vb) {
  __shared__ bf16 As[128*64];   // 16 KB, rows of 64 with chunk swizzle
  __shared__ bf16 Bs[128*64];   // 16 KB
  const int tid = threadIdx.x;
  const int lane = tid & 63, wave = tid >> 6;
  const int quad = lane >> 4, l16 = lane & 15;
  const int wm = (wave >> 1) * 64, wn = (wave & 1) * 64;
  const int m0  = blockIdx.x * 128;
  const int nt0 = blockIdx.y * 128;          // 0..3071
  const int which = nt0 >> 10;               // 0=Q 1=K 2=V
  const int n0 = nt0 & 1023;
  const bf16* W = Wt + ((size_t)which << 20);
  const float* bias = which==0 ? bq : (which==1 ? bk : bv);
  const bool vmode = (which == 2);
  const float oscale = (which==0) ? 0.125f * 1.44269504088896340736f : 1.0f;

  f32x4 acc[4][4];
  #pragma unroll
  for (int i=0;i<4;i++)
    #pragma unroll
    for (int j=0;j<4;j++) acc[i][j] = (f32x4){0.f,0.f,0.f,0.f};

  for (int k0 = 0; k0 < 1024; k0 += 64) {
    __syncthreads();
    #pragma unroll
    for (int it=0; it<4; ++it) {
      int id = tid + it*256;               // 0..1023 slots of 16B
      int row = id >> 3, seg = id & 7;
      int c = ((seg ^ (row & 7)) << 3);    // swizzled source chunk
      async16(X + (size_t)(m0+row)*1024 + k0 + c, (char*)As + id*16);
      async16(W + (size_t)(n0+row)*1024 + k0 + c, (char*)Bs + id*16);
    }
    __syncthreads();   // drains vmcnt before barrier -> LDS valid
    const bf16* Asrc = vmode ? Bs : As;
    const bf16* Bsrc = vmode ? As : Bs;
    #pragma unroll
    for (int ks=0; ks<2; ++ks) {
      short8 af[4], bfv[4];
      #pragma unroll
      for (int i=0;i<4;i++) {
        const int row = wm + i*16 + l16;
        af[i] = *(const short8*)(Asrc + row*64 + (((ks*4+quad) ^ (row&7)) << 3));
      }
      #pragma unroll
      for (int j=0;j<4;j++) {
        const int row = wn + j*16 + l16;
        bfv[j] = *(const short8*)(Bsrc + row*64 + (((ks*4+quad) ^ (row&7)) << 3));
      }
      #pragma unroll
      for (int i=0;i<4;i++)
        #pragma unroll
        for (int j=0;j<4;j++)
          acc[i][j] = __builtin_amdgcn_mfma_f32_16x16x32_bf16(af[i], bfv[j], acc[i][j], 0, 0, 0);
    }
  }

  if (!vmode) {
    bf16* out = (which==0) ? Qb : Kb;
    #pragma unroll
    for (int i=0;i<4;i++) {
      #pragma unroll
      for (int j=0;j<4;j++) {
        const int n = n0 + wn + j*16 + l16;
        const float bvv = bias[n];
        const int h = n >> 6, hd = n & 63;
        #pragma unroll
        for (int r=0;r<4;r++) {
          const int m = m0 + wm + i*16 + quad*4 + r;
          const int b = m >> 11, t = m & 2047;
          out[(((size_t)b*H_ + h)*T_ + t)*HD_ + hd] = __float2bfloat16((acc[i][j][r] + bvv) * oscale);
        }
      }
    }
  } else {
    #pragma unroll
    for (int i=0;i<4;i++) {
      #pragma unroll
      for (int r=0;r<4;r++) {
        const int n = n0 + wm + i*16 + quad*4 + r;
        const float bvv = bias[n];
        const int h = n >> 6, hd = n & 63;
        #pragma unroll
        for (int j=0;j<4;j++) {
          const int m = m0 + wn + j*16 + l16;
          const int b = m >> 11, t = m & 2047;
          Vb[(((size_t)b*H_ + h)*HD_ + hd)*T_ + t] = __float2bfloat16(acc[i][j][r] + bvv);
        }
      }
    }
  }
}

// ---------------- flash attention v5 (round-6 known-good): 64q x 32k per wave, key-split waves ----------------
// swizzled LDS tile: 64 rows x 64 bf16; chunk (8 elems) stored at (chunk ^ (row&7))
__device__ __forceinline__ void stage64x64(const bf16* __restrict__ g, size_t gstride, bf16* lds,
                                           int wave, int lane) {
  const int lr = lane >> 3;           // row within 8-row group
  const int c  = (lane & 7) ^ lr;     // global chunk this lane fetches
  #pragma unroll
  for (int it = 0; it < 2; ++it) {
    const int group = wave * 2 + it;  // 0..7
    async16(g + (size_t)(group*8 + lr)*gstride + c*8, lds + group*512 + lane*8);
  }
}

__device__ __forceinline__ short8 read_swz(const bf16* lds, int row, int chunk) {
  return *(const short8*)(lds + row*64 + ((chunk ^ (row & 7)) << 3));
}

#define PSTR 36   // P strip stride (bf16), 32 keys + pad

__global__ __launch_bounds__(256,2) void attn_kernel(const bf16* __restrict__ Qg, const bf16* __restrict__ Kg,
                                                     const bf16* __restrict__ Vg, bf16* __restrict__ Og) {
  __shared__ bf16 Qs[128*64];         // 128 q-rows swizzled; reused as fp32 O-exchange (16KB)
  __shared__ bf16 Kd[2][64*64];       // double-buffered keys x hd
  __shared__ bf16 Vd[2][64*64];       // double-buffered hd x keys
  __shared__ bf16 Ps[4][4][16*PSTR];  // per-wave, per-strip P [query16][key32]
  __shared__ float Lred[2][2][4][16]; // [qhalf][khalf][strip][q16]

  const int tid = threadIdx.x;
  const int lane = tid & 63, wave = tid >> 6;
  const int quad = lane >> 4, l16 = lane & 15;
  const int qhalf = wave & 1, khalf = wave >> 1;
  const int bh = blockIdx.y;
  const int q0 = blockIdx.x * 128;

  const bf16* Qp = Qg + (size_t)bh*T_*HD_;
  const bf16* Kp = Kg + (size_t)bh*T_*HD_;
  const bf16* Vp = Vg + (size_t)bh*HD_*T_;

  stage64x64(Qp + (size_t)q0*HD_,      HD_, Qs,       wave, lane);
  stage64x64(Qp + (size_t)(q0+64)*HD_, HD_, Qs+64*64, wave, lane);
  stage64x64(Kp, HD_, Kd[0], wave, lane);
  stage64x64(Vp, T_,  Vd[0], wave, lane);
  __syncthreads();

  short8 qf[4][2];   // [strip][ks]; strip s covers queries qhalf*64 + s*16 + [0,16)
  #pragma unroll
  for (int s=0; s<4; ++s)
    #pragma unroll
    for (int ks=0; ks<2; ++ks)
      qf[s][ks] = read_swz(Qs, qhalf*64 + s*16 + l16, ks*4 + quad);

  f32x4 o_acc[4][4];
  float l_part[4] = {0.f, 0.f, 0.f, 0.f};
  #pragma unroll
  for (int s=0;s<4;s++)
    #pragma unroll
    for (int jv=0;jv<4;jv++) o_acc[s][jv] = (f32x4){0.f,0.f,0.f,0.f};

  const int krow = khalf * 32;
  const int NT = T_/64;

  for (int kt=0; kt<NT; ++kt) {
    const int cur = kt & 1;
    if (kt+1 < NT) {
      stage64x64(Kp + (size_t)(kt+1)*64*HD_, HD_, Kd[1-cur], wave, lane);
      stage64x64(Vp + (size_t)(kt+1)*64,     T_,  Vd[1-cur], wave, lane);
    }
    const bf16* Ks  = Kd[cur];
    const bf16* Vts = Vd[cur];

    // this wave's key-half fragments
    short8 kf[2][2];   // [jb][ks]
    #pragma unroll
    for (int jb=0; jb<2; ++jb)
      #pragma unroll
      for (int ks=0; ks<2; ++ks)
        kf[jb][ks] = read_swz(Ks, krow + jb*16 + l16, ks*4 + quad);
    short8 vf[4];      // [jv] : V[key=khalf*32+quad*8+j][hd=jv*16+l16]
    #pragma unroll
    for (int jv=0; jv<4; ++jv)
      vf[jv] = read_swz(Vts, jv*16 + l16, khalf*4 + quad);

    // phase 1: QK + softmax for all strips (stores to per-strip P buffers)
    #pragma unroll
    for (int s=0; s<4; ++s) {
      f32x4 sc[2];
      sc[0] = (f32x4){0.f,0.f,0.f,0.f};
      sc[1] = (f32x4){0.f,0.f,0.f,0.f};
      #pragma unroll
      for (int ks=0; ks<2; ++ks)
        #pragma unroll
        for (int jb=0; jb<2; ++jb)
          sc[jb] = __builtin_amdgcn_mfma_f32_16x16x32_bf16(kf[jb][ks], qf[s][ks], sc[jb], 0, 0, 0);
      bf16* Pw = &Ps[wave][s][0];
      #pragma unroll
      for (int jb=0; jb<2; ++jb) {
        bf16 pk[4];
        #pragma unroll
        for (int r=0; r<4; ++r) {
          float pv = __builtin_amdgcn_exp2f(sc[jb][r]);
          l_part[s] += pv;
          pk[r] = __float2bfloat16(pv);
        }
        *(uint2*)(&Pw[l16*PSTR + jb*16 + quad*4]) = *(const uint2*)pk;
      }
    }

    // phase 2: PV for all strips (one lgkm drain, then MFMA burst)
    #pragma unroll
    for (int s=0; s<4; ++s) {
      short8 pf = *(const short8*)(&Ps[wave][s][l16*PSTR + quad*8]);
      #pragma unroll
      for (int jv=0; jv<4; ++jv)
        o_acc[s][jv] = __builtin_amdgcn_mfma_f32_16x16x32_bf16(pf, vf[jv], o_acc[s][jv], 0, 0, 0);
    }

    __syncthreads();   // all waves done with cur tile; drains prefetch DMA
  }

  // l: reduce over quads (keys within this wave's half), publish, combine key-halves
  #pragma unroll
  for (int s=0; s<4; ++s) {
    float l = l_part[s];
    l += __shfl_xor(l, 16);
    l += __shfl_xor(l, 32);
    l_part[s] = l;
  }
  if (lane < 16) {
    #pragma unroll
    for (int s=0; s<4; ++s) Lred[qhalf][khalf][s][lane] = l_part[s];
  }
  __syncthreads();
  float linv[4][4];
  #pragma unroll
  for (int s=0; s<4; ++s)
    #pragma unroll
    for (int r=0; r<4; ++r)
      linv[s][r] = 1.0f / (Lred[qhalf][0][s][quad*4+r] + Lred[qhalf][1][s][quad*4+r]);

  // O reduction across key-halves through Qs (dead), 2 rounds x 16KB
  f32x4* xb = (f32x4*)Qs;
  #pragma unroll
  for (int round=0; round<2; ++round) {
    const int sB = round*2;
    if (khalf == 1) {
      #pragma unroll
      for (int s2=0; s2<2; ++s2)
        #pragma unroll
        for (int jv=0; jv<4; ++jv)
          xb[qhalf*512 + s2*256 + jv*64 + lane] = o_acc[sB+s2][jv];
    }
    __syncthreads();
    if (khalf == 0) {
      #pragma unroll
      for (int s2=0; s2<2; ++s2)
        #pragma unroll
        for (int jv=0; jv<4; ++jv)
          o_acc[sB+s2][jv] += xb[qhalf*512 + s2*256 + jv*64 + lane];
    }
    __syncthreads();
  }

  // epilogue: khalf==0 waves hold full sums; write O as [b][t][h*64+hd]
  if (khalf == 0) {
    const int b = bh >> 4, h = bh & 15;
    #pragma unroll
    for (int s=0; s<4; ++s)
      #pragma unroll
      for (int jv=0; jv<4; ++jv)
        #pragma unroll
        for (int r=0; r<4; ++r) {
          const int row = q0 + qhalf*64 + s*16 + quad*4 + r;
          const float ov = o_acc[s][jv][r] * linv[s][r];
          Og[((size_t)b*T_ + row)*D_ + h*HD_ + jv*16 + l16] = __float2bfloat16(ov);
        }
  }
}

// ---------------- output projection + bias + residual(fp32) -> fp32 tmp ----------------
// 128x64 tile, BK=64 + XOR swizzle; grid 32x16 = 512 blocks = 2/CU
__global__ __launch_bounds__(256,2) void proj_gemm(const bf16* __restrict__ A, const bf16* __restrict__ Wt,
                                                   const float* __restrict__ bo, const float* __restrict__ Xres,
                                                   float* __restrict__ tmp) {
  __shared__ bf16 As[128*64];   // 16 KB
  __shared__ bf16 Bs[64*64];    // 8 KB
  const int tid = threadIdx.x;
  const int lane = tid & 63, wave = tid >> 6;
  const int quad = lane >> 4, l16 = lane & 15;
  const int wm = wave * 32;
  const int m0 = blockIdx.x * 128;
  const int n0 = blockIdx.y * 64;

  f32x4 acc[2][4];
  #pragma unroll
  for (int i=0;i<2;i++)
    #pragma unroll
    for (int j=0;j<4;j++) acc[i][j] = (f32x4){0.f,0.f,0.f,0.f};

  for (int k0 = 0; k0 < 1024; k0 += 64) {
    __syncthreads();
    #pragma unroll
    for (int it=0; it<4; ++it) {
      int id = tid + it*256;
      int row = id >> 3, seg = id & 7;
      int c = ((seg ^ (row & 7)) << 3);
      async16(A + (size_t)(m0+row)*1024 + k0 + c, (char*)As + id*16);
    }
    #pragma unroll
    for (int it=0; it<2; ++it) {
      int id = tid + it*256;               // 0..511
      int row = id >> 3, seg = id & 7;
      int c = ((seg ^ (row & 7)) << 3);
      async16(Wt + (size_t)(n0+row)*1024 + k0 + c, (char*)Bs + id*16);
    }
    __syncthreads();
    #pragma unroll
    for (int ks=0; ks<2; ++ks) {
      short8 af[2], bfv[4];
      #pragma unroll
      for (int i=0;i<2;i++) {
        const int row = wm + i*16 + l16;
        af[i] = *(const short8*)(As + row*64 + (((ks*4+quad) ^ (row&7)) << 3));
      }
      #pragma unroll
      for (int j=0;j<4;j++) {
        const int row = j*16 + l16;
        bfv[j] = *(const short8*)(Bs + row*64 + (((ks*4+quad) ^ (row&7)) << 3));
      }
      #pragma unroll
      for (int i=0;i<2;i++)
        #pragma unroll
        for (int j=0;j<4;j++)
          acc[i][j] = __builtin_amdgcn_mfma_f32_16x16x32_bf16(af[i], bfv[j], acc[i][j], 0, 0, 0);
    }
  }

  #pragma unroll
  for (int i=0;i<2;i++) {
    #pragma unroll
    for (int j=0;j<4;j++) {
      const int n = n0 + j*16 + l16;
      const float bvv = bo[n];
      #pragma unroll
      for (int r=0;r<4;r++) {
        const int m = m0 + wm + i*16 + quad*4 + r;
        tmp[(size_t)m*1024 + n] = acc[i][j][r] + bvv + Xres[(size_t)m*1024 + n];
      }
    }
  }
}

// ---------------- row LayerNorm: tmp fp32 [4096][1024] -> fp32 out ----------------
__global__ __launch_bounds__(256) void ln_kernel(const float* __restrict__ tmp, const float* __restrict__ g,
                                                 const float* __restrict__ b, float* __restrict__ out) {
  const int row = blockIdx.x;
  const int tid = threadIdx.x;
  const float* p = tmp + (size_t)row*D_;
  float4 v = *(const float4*)(p + tid*4);
  float s  = v.x + v.y + v.z + v.w;
  float sq = v.x*v.x + v.y*v.y + v.z*v.z + v.w*v.w;
  #pragma unroll
  for (int off=32; off>0; off>>=1) { s += __shfl_down(s, off); sq += __shfl_down(sq, off); }
  __shared__ float red[8];
  __shared__ float stats[2];
  const int wave = tid >> 6, lane = tid & 63;
  if (lane == 0) { red[wave] = s; red[4+wave] = sq; }
  __syncthreads();
  if (tid == 0) {
    float S = red[0]+red[1]+red[2]+red[3];
    float Q = red[4]+red[5]+red[6]+red[7];
    float mu = S * (1.0f/D_);
    float var = Q * (1.0f/D_) - mu*mu;
    stats[0] = mu;
    stats[1] = rsqrtf(var + 1e-5f);
  }
  __syncthreads();
  const float mu = stats[0], rstd = stats[1];
  const float vals[4] = {v.x, v.y, v.z, v.w};
  float4 o;
  float* op = (float*)&o;
  #pragma unroll
  for (int c=0;c<4;c++) op[c] = (vals[c]-mu)*rstd*g[tid*4+c] + b[tid*4+c];
  *(float4*)(out + (size_t)row*D_ + tid*4) = o;
}

extern "C" void kernel_launch(void* const* d_in, const int* in_sizes, int n_in,
                              void* d_out, int out_size, void* d_ws, size_t ws_size,
                              hipStream_t stream) {
  (void)in_sizes; (void)n_in; (void)out_size; (void)ws_size;
  const float* x  = (const float*)d_in[0];
  const float* Wq = (const float*)d_in[1];
  const float* bq = (const float*)d_in[2];
  const float* Wk = (const float*)d_in[3];
  const float* bk = (const float*)d_in[4];
  const float* Wv = (const float*)d_in[5];
  const float* bv = (const float*)d_in[6];
  const float* Wo = (const float*)d_in[7];
  const float* bo = (const float*)d_in[8];
  const float* lg = (const float*)d_in[9];
  const float* lb = (const float*)d_in[10];
  float* out = (float*)d_out;

  char* ws = (char*)d_ws;
  bf16* wt  = (bf16*)ws;  ws += (size_t)4*1024*1024*sizeof(bf16);   // W transposed, bf16 (8 MB)
  bf16* Xb  = (bf16*)ws;  ws += (size_t)M_*D_*sizeof(bf16);         // x bf16 (8 MB)
  bf16* Vb  = (bf16*)ws;  ws += (size_t)M_*D_*sizeof(bf16);         // V^T (8 MB)
  bf16* Ob  = (bf16*)ws;  ws += (size_t)M_*D_*sizeof(bf16);         // attn out (8 MB)
  bf16* Qb  = (bf16*)ws;  ws += (size_t)M_*D_*sizeof(bf16);         // Q (8 MB)
  bf16* Kb  = (bf16*)ws;  ws += (size_t)M_*D_*sizeof(bf16);         // K (8 MB)
  float* tmp = (float*)Qb;   // fp32 [4096][1024] overlays Q+K (dead after attention)

  prep_kernel<<<dim3(32,32,5), dim3(32,8), 0, stream>>>(Wq, Wk, Wv, Wo, x, wt, Xb);
  qkv_gemm<<<dim3(32,24), 256, 0, stream>>>(Xb, wt, bq, bk, bv, Qb, Kb, Vb);
  attn_kernel<<<dim3(T_/128, B_*H_), 256, 0, stream>>>(Qb, Kb, Vb, Ob);
  proj_gemm<<<dim3(32,16), 256, 0, stream>>>(Ob, wt + (size_t)3*1024*1024, bo, x, tmp);
  ln_kernel<<<M_, 256, 0, stream>>>(tmp, lg, lb, out);
}